// Round 4
// baseline (1665.927 us; speedup 1.0000x reference)
//
#include <hip/hip_runtime.h>

#define B_TOT 16384
#define HD 256
#define ID 128
#define BT 32
#define NSTEP 8
#define YP 264   // activation LDS pitch (f16): 132 dwords -> 4-bank row shift
#define XP 136

typedef float    f32x4  __attribute__((ext_vector_type(4)));
typedef float    f32x16 __attribute__((ext_vector_type(16)));
typedef _Float16 f16x8  __attribute__((ext_vector_type(8)));
typedef _Float16 f16x4  __attribute__((ext_vector_type(4)));
typedef _Float16 f16x2  __attribute__((ext_vector_type(2)));

__device__ __forceinline__ float fast_rcp(float x){ return __builtin_amdgcn_rcpf(x); }
__device__ __forceinline__ float fast_exp2(float x){ return __builtin_amdgcn_exp2f(x); }
__device__ __forceinline__ float fast_tanh(float x){
  return 1.0f - 2.0f*fast_rcp(1.0f + fast_exp2(x*2.8853900817779268f));
}
__device__ __forceinline__ float fast_sigmoid(float x){
  return fast_rcp(1.0f + fast_exp2(x*-1.4426950408889634f));
}

// one launch: convert W1, W2, W_ih, W_hh f32->f16 into workspace
__global__ void cvt4(const float* __restrict__ s0, const float* __restrict__ s1,
                     const float* __restrict__ s2, const float* __restrict__ s3,
                     _Float16* __restrict__ d){
  int i = blockIdx.x*256 + threadIdx.x;   // 131072 float4 total
  const float* s; int j;
  if      (i <  16384){ s = s0; j = i; }
  else if (i <  32768){ s = s1; j = i - 16384; }
  else if (i <  65536){ s = s2; j = i - 32768; }
  else                { s = s3; j = i - 65536; }
  float4 v = ((const float4*)s)[j];
  f16x4 t = {(_Float16)v.x, (_Float16)v.y, (_Float16)v.z, (_Float16)v.w};
  *(f16x4*)(d + (size_t)i*4) = t;
}

#define KP(i) ((float)kpk[i][pk][hw])

__global__ __launch_bounds__(512, 2)
void ode_lstm(const float* __restrict__ inputs, const float* __restrict__ h0,
              const float* __restrict__ c0,     const float* __restrict__ ts,
              const float* __restrict__ b_ih,   const float* __restrict__ b_hh,
              const float* __restrict__ b1,     const float* __restrict__ b2,
              const _Float16* __restrict__ W1h, const _Float16* __restrict__ W2h,
              const _Float16* __restrict__ Wihh,const _Float16* __restrict__ Whhh,
              float* __restrict__ out)
{
  __shared__ __align__(16) _Float16 yl[BT*YP];   // stage argument y
  __shared__ __align__(16) _Float16 ul[BT*YP];   // tanh hidden / h1
  __shared__ __align__(16) _Float16 zl[BT*YP];   // z = W2 u + b2 (f16)
  __shared__ __align__(16) _Float16 xl[BT*XP];
  __shared__ __align__(16) float bsl[4*HD];
  __shared__ float dtl[BT];

  const int tid  = threadIdx.x;
  const int wv   = tid >> 6;        // waves 0-3: W1 ("P1"); 4-7: W2 ("P2")
  const int lane = tid & 63;
  const int l31  = lane & 31;       // batch row (C-layout col / A-operand m / B-operand n)
  const int hh   = lane >> 5;       // k-half for operands; +4 feat in C/D
  const int row0 = blockIdx.x * BT;
  const int p1   = (wv < 4);
  const int fb   = (wv & 3) * 64;   // GEMM role: 64-feat strip base (2 sub-strips of 32)
  const int cb   = wv*32 + hh*4;    // epilogue state slice (R2 layout, all 8 waves)
  const int yrow = l31*YP + cb;     // state-slice LDS offset
  const int wrow = l31*YP + fb + 4*hh; // GEMM-role write offset (+st*32+8*g2)

  // ---- prologue staging ----
  #pragma unroll
  for (int it = 0; it < 2; ++it){
    int idx = tid + it*512;                 // 32 rows * 32 float4
    int r = idx >> 5, c4 = idx & 31;
    float4 v = ((const float4*)inputs)[(size_t)(row0 + r)*(ID/4) + c4];
    f16x4 t = {(_Float16)v.x, (_Float16)v.y, (_Float16)v.z, (_Float16)v.w};
    *(f16x4*)(xl + r*XP + c4*4) = t;
  }
  bsl[tid]       = b_ih[tid]       + b_hh[tid];
  bsl[tid + 512] = b_ih[tid + 512] + b_hh[tid + 512];
  if (tid < BT) dtl[tid] = ts[row0 + tid] * (1.0f/NSTEP);

  // ---- role weights: 64-feat strip of ONE matrix, f16, held in regs ----
  f16x8 Wf[2][16];
  {
    const _Float16* Wsel = p1 ? W1h : W2h;
    #pragma unroll
    for (int st = 0; st < 2; ++st){
      const _Float16* wp = Wsel + (size_t)(fb + st*32 + l31)*HD + hh*8;
      #pragma unroll
      for (int kt = 0; kt < 16; ++kt)
        Wf[st][kt] = *(const f16x8*)(wp + kt*16);
    }
  }
  // role bias (b1 for P1, b2 for P2), f16-packed: 8 regs
  f16x4 bp8[2][4];
  {
    const float* bsrc = p1 ? b1 : b2;
    #pragma unroll
    for (int st = 0; st < 2; ++st)
    #pragma unroll
    for (int g2 = 0; g2 < 4; ++g2){
      f32x4 t = *(const f32x4*)(bsrc + fb + st*32 + 8*g2 + 4*hh);
      f16x4 p; 
      #pragma unroll
      for (int r3 = 0; r3 < 4; ++r3) p[r3] = (_Float16)t[r3];
      bp8[st][g2] = p;
    }
  }

  // ---- master h (fp32 regs, R2 state slice) + initial y = h0 ----
  f32x4 h4[4];
  #pragma unroll
  for (int g2 = 0; g2 < 4; ++g2){
    f32x4 hv = *(const f32x4*)(h0 + (size_t)(row0 + l31)*HD + cb + 8*g2);
    h4[g2] = hv;
    f16x4 t = {(_Float16)hv[0], (_Float16)hv[1], (_Float16)hv[2], (_Float16)hv[3]};
    *(f16x4*)(yl + yrow + 8*g2) = t;
  }
  __syncthreads();
  const float dtv = dtl[l31];

  // one phase = u = tanh(W1 y + b1) -> ul   (P1 waves)
  //             z = W2 u + b2       -> zl   (P2 waves)
  // B-frag shared across the wave's 2 sub-strips: halves LDS read traffic.
  auto do_phase = [&](){
    if (p1){
      f32x16 a0 = {}, a1 = {};
      const _Float16* bp = yl + l31*YP + hh*8;
      #pragma unroll 4
      for (int kt = 0; kt < 16; ++kt){
        f16x8 Bf = *(const f16x8*)(bp + kt*16);
        a0 = __builtin_amdgcn_mfma_f32_32x32x16_f16(Wf[0][kt], Bf, a0, 0, 0, 0);
        a1 = __builtin_amdgcn_mfma_f32_32x32x16_f16(Wf[1][kt], Bf, a1, 0, 0, 0);
      }
      #pragma unroll
      for (int g2 = 0; g2 < 4; ++g2){
        f16x4 u0, u1;
        #pragma unroll
        for (int r3 = 0; r3 < 4; ++r3){
          u0[r3] = (_Float16)fast_tanh(a0[g2*4+r3] + (float)bp8[0][g2][r3]);
          u1[r3] = (_Float16)fast_tanh(a1[g2*4+r3] + (float)bp8[1][g2][r3]);
        }
        *(f16x4*)(ul + wrow + 8*g2)      = u0;
        *(f16x4*)(ul + wrow + 32 + 8*g2) = u1;
      }
    }
    __syncthreads();                       // S1: ul ready
    if (!p1){
      f32x16 a0 = {}, a1 = {};
      const _Float16* bp = ul + l31*YP + hh*8;
      #pragma unroll 4
      for (int kt = 0; kt < 16; ++kt){
        f16x8 Bf = *(const f16x8*)(bp + kt*16);
        a0 = __builtin_amdgcn_mfma_f32_32x32x16_f16(Wf[0][kt], Bf, a0, 0, 0, 0);
        a1 = __builtin_amdgcn_mfma_f32_32x32x16_f16(Wf[1][kt], Bf, a1, 0, 0, 0);
      }
      #pragma unroll
      for (int g2 = 0; g2 < 4; ++g2){
        f16x4 z0, z1;
        #pragma unroll
        for (int r3 = 0; r3 < 4; ++r3){
          z0[r3] = (_Float16)(a0[g2*4+r3] + (float)bp8[0][g2][r3]);
          z1[r3] = (_Float16)(a1[g2*4+r3] + (float)bp8[1][g2][r3]);
        }
        *(f16x4*)(zl + wrow + 8*g2)      = z0;
        *(f16x4*)(zl + wrow + 32 + 8*g2) = z1;
      }
    }
    __syncthreads();                       // S2: zl ready
  };

  // epilogue (ALL waves, R2 state slice): kd from zl, update kpk, write next y
  #define STAGE(SIDX, YEXPR)                                                \
    do_phase();                                                             \
    { _Pragma("unroll")                                                     \
      for (int g2 = 0; g2 < 4; ++g2){                                       \
        f16x4 zv = *(const f16x4*)(zl + yrow + 8*g2);                       \
        f16x4 yv;                                                           \
        _Pragma("unroll")                                                   \
        for (int r3 = 0; r3 < 4; ++r3){                                     \
          const int r = g2*4 + r3; const int pk = r>>1; const int hw = r&1; \
          float kd = dtv*(float)zv[r3];                                     \
          if (SIDX < 5) kpk[SIDX][pk][hw] = (_Float16)kd;                   \
          yv[r3] = (_Float16)(YEXPR);                                       \
        }                                                                   \
        *(f16x4*)(yl + yrow + 8*g2) = yv;                                   \
      }                                                                     \
    }                                                                       \
    __syncthreads();  /* S3: yl ready */

  // ================= RK45 (Dormand-Prince) =================
  #pragma unroll 1
  for (int step = 0; step < NSTEP; ++step){
    f16x2 kpk[5][8];   // dt-scaled slopes k1..k5, f16-packed, 40 VGPR

    STAGE(0, h4[g2][r3] + 0.2f*kd)
    STAGE(1, h4[g2][r3] + 0.075f*KP(0) + 0.225f*kd)
    STAGE(2, h4[g2][r3] + (44.0f/45.0f)*KP(0) + (-56.0f/15.0f)*KP(1)
                        + (32.0f/9.0f)*kd)
    STAGE(3, h4[g2][r3] + (19372.0f/6561.0f)*KP(0) + (-25360.0f/2187.0f)*KP(1)
                        + (64448.0f/6561.0f)*KP(2) + (-212.0f/729.0f)*kd)
    STAGE(4, h4[g2][r3] + (9017.0f/3168.0f)*KP(0) + (-355.0f/33.0f)*KP(1)
                        + (46732.0f/5247.0f)*KP(2) + (49.0f/176.0f)*KP(3)
                        + (-5103.0f/18656.0f)*kd)
    // final stage: update master h, write y = h
    do_phase();
    { 
      #pragma unroll
      for (int g2 = 0; g2 < 4; ++g2){
        f16x4 zv = *(const f16x4*)(zl + yrow + 8*g2);
        f16x4 yv;
        #pragma unroll
        for (int r3 = 0; r3 < 4; ++r3){
          const int r = g2*4 + r3; const int pk = r>>1; const int hw = r&1;
          float kd = dtv*(float)zv[r3];
          float hn = h4[g2][r3] + (35.0f/384.0f)*KP(0) + (500.0f/1113.0f)*KP(2)
                   + (125.0f/192.0f)*KP(3) + (-2187.0f/6784.0f)*KP(4)
                   + (11.0f/84.0f)*kd;
          h4[g2][r3] = hn;
          yv[r3] = (_Float16)hn;
        }
        *(f16x4*)(yl + yrow + 8*g2) = yv;
      }
    }
    __syncthreads();
  }

  // ================= two weight-shared LSTM cells (R1-proven, all waves) ====
  f32x16 agx[4] = {};
  {
    const _Float16* bp = xl + l31*XP + hh*8;
    #pragma unroll 2
    for (int kt = 0; kt < 8; ++kt){
      f16x8 Bf = *(const f16x8*)(bp + kt*16);
      #pragma unroll
      for (int g = 0; g < 4; ++g){
        f16x8 Af = *(const f16x8*)(Wihh + (size_t)(g*HD + wv*32 + l31)*ID + kt*16 + hh*8);
        agx[g] = __builtin_amdgcn_mfma_f32_32x32x16_f16(Af, Bf, agx[g], 0, 0, 0);
      }
    }
  }
  f32x4 c4[4];
  #pragma unroll
  for (int g2 = 0; g2 < 4; ++g2)
    c4[g2] = *(const f32x4*)(c0 + (size_t)(row0 + l31)*HD + cb + 8*g2);

  #pragma unroll 1
  for (int cell = 0; cell < 2; ++cell){
    f32x16 ag[4];
    #pragma unroll
    for (int g = 0; g < 4; ++g) ag[g] = agx[g];
    const _Float16* hsrc = (cell == 0) ? yl : ul;
    const _Float16* bp = hsrc + l31*YP + hh*8;
    #pragma unroll 2
    for (int kt = 0; kt < 16; ++kt){
      f16x8 Bf = *(const f16x8*)(bp + kt*16);
      #pragma unroll
      for (int g = 0; g < 4; ++g){
        f16x8 Af = *(const f16x8*)(Whhh + (size_t)(g*HD + wv*32 + l31)*HD + kt*16 + hh*8);
        ag[g] = __builtin_amdgcn_mfma_f32_32x32x16_f16(Af, Bf, ag[g], 0, 0, 0);
      }
    }
    #pragma unroll
    for (int g2 = 0; g2 < 4; ++g2){
      f32x4 bi = *(const f32x4*)(bsl + 0*HD + cb + 8*g2);
      f32x4 bf = *(const f32x4*)(bsl + 1*HD + cb + 8*g2);
      f32x4 bg = *(const f32x4*)(bsl + 2*HD + cb + 8*g2);
      f32x4 bo = *(const f32x4*)(bsl + 3*HD + cb + 8*g2);
      f16x4 hv; f32x4 ho, co;
      #pragma unroll
      for (int r3 = 0; r3 < 4; ++r3){
        const int r = g2*4 + r3;
        float iv = fast_sigmoid(ag[0][r] + bi[r3]);
        float fv = fast_sigmoid(ag[1][r] + bf[r3]);
        float gv = fast_tanh   (ag[2][r] + bg[r3]);
        float ov = fast_sigmoid(ag[3][r] + bo[r3]);
        float cn = fv*c4[g2][r3] + iv*gv;
        c4[g2][r3] = cn;
        float hn = ov*fast_tanh(cn);
        hv[r3] = (_Float16)hn; ho[r3] = hn; co[r3] = cn;
      }
      if (cell == 0){
        *(f16x4*)(ul + yrow + 8*g2) = hv;          // h1 -> cell2 input
      } else {
        size_t o = (size_t)(row0 + l31)*HD + cb + 8*g2;
        *(f32x4*)(out + o) = ho;                   // h2
        *(f32x4*)(out + (size_t)B_TOT*HD + o) = co;// c2
      }
    }
    if (cell == 0) __syncthreads();
  }
}

extern "C" void kernel_launch(void* const* d_in, const int* in_sizes, int n_in,
                              void* d_out, int out_size, void* d_ws, size_t ws_size,
                              hipStream_t stream) {
  (void)in_sizes; (void)n_in; (void)out_size; (void)ws_size;
  const float* inputs = (const float*)d_in[0];
  const float* h0     = (const float*)d_in[1];
  const float* c0     = (const float*)d_in[2];
  const float* ts     = (const float*)d_in[3];
  const float* W_ih   = (const float*)d_in[4];
  const float* W_hh   = (const float*)d_in[5];
  const float* b_ih   = (const float*)d_in[6];
  const float* b_hh   = (const float*)d_in[7];
  const float* W1     = (const float*)d_in[8];
  const float* b1     = (const float*)d_in[9];
  const float* W2     = (const float*)d_in[10];
  const float* b2     = (const float*)d_in[11];
  float* out = (float*)d_out;

  _Float16* wsh  = (_Float16*)d_ws;
  _Float16* W1h  = wsh;             // 65536 f16
  _Float16* W2h  = wsh + 65536;     // 65536
  _Float16* Wihh = wsh + 131072;    // 131072
  _Float16* Whhh = wsh + 262144;    // 262144  (total 1 MB)

  // single conversion launch: 131072 float4 across W1|W2|W_ih|W_hh
  cvt4<<<512, 256, 0, stream>>>(W1, W2, W_ih, W_hh, wsh);

  ode_lstm<<<B_TOT/BT, 512, 0, stream>>>(inputs, h0, c0, ts, b_ih, b_hh, b1, b2,
                                         W1h, W2h, Wihh, Whhh, out);
}

// Round 5
// 420.334 us; speedup vs baseline: 3.9633x; 3.9633x over previous
//
#include <hip/hip_runtime.h>

#define B_TOT 16384
#define HD 256
#define ID 128
#define BT 32
#define NSTEP 8
#define YP 264   // y/u LDS pitch (f16): 132 dwords -> 4-bank row shift, b128 reads at ~bank floor
#define XP 136

typedef float    f32x4  __attribute__((ext_vector_type(4)));
typedef float    f32x16 __attribute__((ext_vector_type(16)));
typedef _Float16 f16x8  __attribute__((ext_vector_type(8)));
typedef _Float16 f16x4  __attribute__((ext_vector_type(4)));
typedef _Float16 f16x2  __attribute__((ext_vector_type(2)));

__device__ __forceinline__ float fast_rcp(float x){ return __builtin_amdgcn_rcpf(x); }
__device__ __forceinline__ float fast_exp2(float x){ return __builtin_amdgcn_exp2f(x); }
__device__ __forceinline__ float fast_tanh(float x){
  return 1.0f - 2.0f*fast_rcp(1.0f + fast_exp2(x*2.8853900817779268f));
}
__device__ __forceinline__ float fast_sigmoid(float x){
  return fast_rcp(1.0f + fast_exp2(x*-1.4426950408889634f));
}

// one launch: convert W1 | W2 | W_ih | W_hh  f32->f16 into contiguous workspace
__global__ void cvt4(const float* __restrict__ s0, const float* __restrict__ s1,
                     const float* __restrict__ s2, const float* __restrict__ s3,
                     _Float16* __restrict__ d){
  int i = blockIdx.x*256 + threadIdx.x;   // 131072 float4 total
  const float* s; int j;
  if      (i <  16384){ s = s0; j = i; }
  else if (i <  32768){ s = s1; j = i - 16384; }
  else if (i <  65536){ s = s2; j = i - 32768; }
  else                { s = s3; j = i - 65536; }
  float4 v = ((const float4*)s)[j];
  f16x4 t = {(_Float16)v.x, (_Float16)v.y, (_Float16)v.z, (_Float16)v.w};
  *(f16x4*)(d + (size_t)i*4) = t;
}

// element r of f32x16 acc: feat = 32*wv + 8*(r>>2) + 4*hh + (r&3), batch = l31
#define KP(i) ((float)kpk[i][pk][hw])

__global__ __launch_bounds__(512, 2)
void ode_lstm(const float* __restrict__ inputs, const float* __restrict__ h0,
              const float* __restrict__ c0,     const float* __restrict__ ts,
              const float* __restrict__ b_ih,   const float* __restrict__ b_hh,
              const float* __restrict__ b1,     const float* __restrict__ b2,
              const _Float16* __restrict__ W1h, const _Float16* __restrict__ W2h,
              const _Float16* __restrict__ Wihh,const _Float16* __restrict__ Whhh,
              float* __restrict__ out)
{
  __shared__ __align__(16) _Float16 yl[BT*YP];
  __shared__ __align__(16) _Float16 ul[BT*YP];
  __shared__ __align__(16) _Float16 xl[BT*XP];
  __shared__ __align__(16) float b1l[HD], b2l[HD], bsl[4*HD];
  __shared__ float dtl[BT];

  const int tid  = threadIdx.x;
  const int wv   = tid >> 6;        // 8 waves: feature strip 32*wv
  const int lane = tid & 63;
  const int l31  = lane & 31;       // batch row owned by this lane (C-layout col)
  const int hh   = lane >> 5;       // k-half for A/B operands; +4 feat offset in C/D
  const int row0 = blockIdx.x * BT;
  const int cb   = wv*32 + hh*4;    // lane feature base; +8*g2 per acc group
  const int yrow = l31*YP + cb;     // LDS elem offset for this lane's stage writes

  // ---- prologue staging ----
  #pragma unroll
  for (int it = 0; it < 2; ++it){
    int idx = tid + it*512;                 // 32 rows * 32 float4
    int r = idx >> 5, c4 = idx & 31;
    float4 v = ((const float4*)inputs)[(size_t)(row0 + r)*(ID/4) + c4];
    f16x4 t = {(_Float16)v.x, (_Float16)v.y, (_Float16)v.z, (_Float16)v.w};
    *(f16x4*)(xl + r*XP + c4*4) = t;
  }
  if (tid < HD){ b1l[tid] = b1[tid]; b2l[tid] = b2[tid]; }
  bsl[tid]       = b_ih[tid]       + b_hh[tid];
  bsl[tid + 512] = b_ih[tid + 512] + b_hh[tid + 512];
  if (tid < BT) dtl[tid] = ts[row0 + tid] * (1.0f/NSTEP);

  // ---- W1, W2 strips held in VGPRs for the whole RK45 loop ----
  f16x8 W1f[16], W2f[16];
  {
    const _Float16* w1p = W1h + (size_t)(wv*32 + l31)*HD + hh*8;
    const _Float16* w2p = W2h + (size_t)(wv*32 + l31)*HD + hh*8;
    #pragma unroll
    for (int kt = 0; kt < 16; ++kt){
      W1f[kt] = *(const f16x8*)(w1p + kt*16);
      W2f[kt] = *(const f16x8*)(w2p + kt*16);
    }
  }

  // ---- master h (fp32 regs) + initial y = h0 ----
  f32x4 h4[4];
  #pragma unroll
  for (int g2 = 0; g2 < 4; ++g2){
    f32x4 hv = *(const f32x4*)(h0 + (size_t)(row0 + l31)*HD + cb + 8*g2);
    h4[g2] = hv;
    f16x4 t = {(_Float16)hv[0], (_Float16)hv[1], (_Float16)hv[2], (_Float16)hv[3]};
    *(f16x4*)(yl + yrow + 8*g2) = t;
  }
  __syncthreads();
  const float dtv = dtl[l31];

  // GEMM: acc(feat=32wv strip, batch=all 32) += Wregs * act ; act read from LDS only
  auto gemm16 = [&](const f16x8 (&Wf)[16], const _Float16* __restrict__ act)->f32x16{
    f32x16 a = {};
    const _Float16* bp = act + l31*YP + hh*8;
    #pragma unroll
    for (int kt = 0; kt < 16; ++kt){
      f16x8 Bf = *(const f16x8*)(bp + kt*16);
      a = __builtin_amdgcn_mfma_f32_32x32x16_f16(Wf[kt], Bf, a, 0, 0, 0);
    }
    return a;
  };

  // phase1: u = tanh(W1 y + b1) -> ul
  auto phase1 = [&](){
    f32x16 a = gemm16(W1f, yl);
    #pragma unroll
    for (int g2 = 0; g2 < 4; ++g2){
      f32x4 bv = *(const f32x4*)(b1l + cb + 8*g2);
      f16x4 uv;
      #pragma unroll
      for (int r3 = 0; r3 < 4; ++r3)
        uv[r3] = (_Float16)fast_tanh(a[g2*4 + r3] + bv[r3]);
      *(f16x4*)(ul + yrow + 8*g2) = uv;
    }
    __syncthreads();
  };

  #define STAGE(SIDX, YEXPR)                                              \
    phase1();                                                             \
    { f32x16 a2 = gemm16(W2f, ul);                                        \
      _Pragma("unroll")                                                   \
      for (int g2 = 0; g2 < 4; ++g2){                                     \
        f32x4 bv = *(const f32x4*)(b2l + cb + 8*g2);                      \
        f16x4 yv;                                                         \
        _Pragma("unroll")                                                 \
        for (int r3 = 0; r3 < 4; ++r3){                                   \
          const int r = g2*4 + r3; const int pk = r>>1; const int hw = r&1;\
          float kd = dtv*(a2[r] + bv[r3]);                                \
          if (SIDX < 5) kpk[SIDX][pk][hw] = (_Float16)kd;                 \
          yv[r3] = (_Float16)(YEXPR);                                     \
        }                                                                 \
        *(f16x4*)(yl + yrow + 8*g2) = yv;                                 \
      }                                                                   \
    }                                                                     \
    __syncthreads();

  // ================= RK45 (Dormand-Prince) =================
  #pragma unroll 1
  for (int step = 0; step < NSTEP; ++step){
    f16x2 kpk[5][8];   // dt-scaled slopes k1..k5, f16-packed, 40 VGPR

    STAGE(0, h4[g2][r3] + 0.2f*kd)
    STAGE(1, h4[g2][r3] + 0.075f*KP(0) + 0.225f*kd)
    STAGE(2, h4[g2][r3] + (44.0f/45.0f)*KP(0) + (-56.0f/15.0f)*KP(1)
                        + (32.0f/9.0f)*kd)
    STAGE(3, h4[g2][r3] + (19372.0f/6561.0f)*KP(0) + (-25360.0f/2187.0f)*KP(1)
                        + (64448.0f/6561.0f)*KP(2) + (-212.0f/729.0f)*kd)
    STAGE(4, h4[g2][r3] + (9017.0f/3168.0f)*KP(0) + (-355.0f/33.0f)*KP(1)
                        + (46732.0f/5247.0f)*KP(2) + (49.0f/176.0f)*KP(3)
                        + (-5103.0f/18656.0f)*kd)
    // final stage: update master h, write y = h (next step / LSTM h-in)
    phase1();
    { f32x16 a2 = gemm16(W2f, ul);
      #pragma unroll
      for (int g2 = 0; g2 < 4; ++g2){
        f32x4 bv = *(const f32x4*)(b2l + cb + 8*g2);
        f16x4 yv;
        #pragma unroll
        for (int r3 = 0; r3 < 4; ++r3){
          const int r = g2*4 + r3; const int pk = r>>1; const int hw = r&1;
          float kd = dtv*(a2[r] + bv[r3]);
          float hn = h4[g2][r3] + (35.0f/384.0f)*KP(0) + (500.0f/1113.0f)*KP(2)
                   + (125.0f/192.0f)*KP(3) + (-2187.0f/6784.0f)*KP(4)
                   + (11.0f/84.0f)*kd;
          h4[g2][r3] = hn;
          yv[r3] = (_Float16)hn;
        }
        *(f16x4*)(yl + yrow + 8*g2) = yv;
      }
    }
    __syncthreads();
  }

  // ================= two weight-shared LSTM cells =================
  f32x4 c4[4];
  #pragma unroll
  for (int g2 = 0; g2 < 4; ++g2)
    c4[g2] = *(const f32x4*)(c0 + (size_t)(row0 + l31)*HD + cb + 8*g2);

  #pragma unroll 1
  for (int cell = 0; cell < 2; ++cell){
    f32x16 ag[4] = {};          // 4 gate accs
    // x-part: K=128 (recomputed per cell — 32 MFMA, trivially cheap)
    {
      const _Float16* bp = xl + l31*XP + hh*8;
      #pragma unroll 4
      for (int kt = 0; kt < 8; ++kt){
        f16x8 Bf = *(const f16x8*)(bp + kt*16);
        #pragma unroll
        for (int g = 0; g < 4; ++g){
          f16x8 Af = *(const f16x8*)(Wihh + (size_t)(g*HD + wv*32 + l31)*ID + kt*16 + hh*8);
          ag[g] = __builtin_amdgcn_mfma_f32_32x32x16_f16(Af, Bf, ag[g], 0, 0, 0);
        }
      }
    }
    // h-part: K=256
    {
      const _Float16* hsrc = (cell == 0) ? yl : ul;
      const _Float16* bp = hsrc + l31*YP + hh*8;
      #pragma unroll 4
      for (int kt = 0; kt < 16; ++kt){
        f16x8 Bf = *(const f16x8*)(bp + kt*16);
        #pragma unroll
        for (int g = 0; g < 4; ++g){
          f16x8 Af = *(const f16x8*)(Whhh + (size_t)(g*HD + wv*32 + l31)*HD + kt*16 + hh*8);
          ag[g] = __builtin_amdgcn_mfma_f32_32x32x16_f16(Af, Bf, ag[g], 0, 0, 0);
        }
      }
    }
    #pragma unroll
    for (int g2 = 0; g2 < 4; ++g2){
      f32x4 bi = *(const f32x4*)(bsl + 0*HD + cb + 8*g2);
      f32x4 bf = *(const f32x4*)(bsl + 1*HD + cb + 8*g2);
      f32x4 bg = *(const f32x4*)(bsl + 2*HD + cb + 8*g2);
      f32x4 bo = *(const f32x4*)(bsl + 3*HD + cb + 8*g2);
      f16x4 hv; f32x4 ho, co;
      #pragma unroll
      for (int r3 = 0; r3 < 4; ++r3){
        const int r = g2*4 + r3;
        float iv = fast_sigmoid(ag[0][r] + bi[r3]);
        float fv = fast_sigmoid(ag[1][r] + bf[r3]);
        float gv = fast_tanh   (ag[2][r] + bg[r3]);
        float ov = fast_sigmoid(ag[3][r] + bo[r3]);
        float cn = fv*c4[g2][r3] + iv*gv;
        c4[g2][r3] = cn;
        float hn = ov*fast_tanh(cn);
        hv[r3] = (_Float16)hn; ho[r3] = hn; co[r3] = cn;
      }
      if (cell == 0){
        *(f16x4*)(ul + yrow + 8*g2) = hv;          // h1 -> cell2 input
      } else {
        size_t o = (size_t)(row0 + l31)*HD + cb + 8*g2;
        *(f32x4*)(out + o) = ho;                   // h2
        *(f32x4*)(out + (size_t)B_TOT*HD + o) = co;// c2
      }
    }
    if (cell == 0) __syncthreads();
  }
}

extern "C" void kernel_launch(void* const* d_in, const int* in_sizes, int n_in,
                              void* d_out, int out_size, void* d_ws, size_t ws_size,
                              hipStream_t stream) {
  (void)in_sizes; (void)n_in; (void)out_size; (void)ws_size;
  const float* inputs = (const float*)d_in[0];
  const float* h0     = (const float*)d_in[1];
  const float* c0     = (const float*)d_in[2];
  const float* ts     = (const float*)d_in[3];
  const float* W_ih   = (const float*)d_in[4];
  const float* W_hh   = (const float*)d_in[5];
  const float* b_ih   = (const float*)d_in[6];
  const float* b_hh   = (const float*)d_in[7];
  const float* W1     = (const float*)d_in[8];
  const float* b1     = (const float*)d_in[9];
  const float* W2     = (const float*)d_in[10];
  const float* b2     = (const float*)d_in[11];
  float* out = (float*)d_out;

  _Float16* wsh  = (_Float16*)d_ws;
  _Float16* W1h  = wsh;             // 65536 f16
  _Float16* W2h  = wsh + 65536;     // 65536
  _Float16* Wihh = wsh + 131072;    // 131072
  _Float16* Whhh = wsh + 262144;    // 262144  (total 1 MB)

  // single conversion launch: 131072 float4 across W1|W2|W_ih|W_hh
  cvt4<<<512, 256, 0, stream>>>(W1, W2, W_ih, W_hh, wsh);

  ode_lstm<<<B_TOT/BT, 512, 0, stream>>>(inputs, h0, c0, ts, b_ih, b_hh, b1, b2,
                                         W1h, W2h, Wihh, Whhh, out);
}